// Round 18
// baseline (71.181 us; speedup 1.0000x reference)
//
#include <hip/hip_runtime.h>
#include <hip/hip_bf16.h>
#include <math.h>

#define BB 16
#define CC 128
#define NN 2048
#define CQ 32   // C/4

typedef __attribute__((ext_vector_type(8))) short bf16x8;
typedef __attribute__((ext_vector_type(4))) float f32x4;
typedef __attribute__((ext_vector_type(16))) float f32x16;
typedef unsigned char uchar;

__device__ __forceinline__ ushort f2b(float f) {
    __hip_bfloat16 h = __float2bfloat16(f);
    return *reinterpret_cast<ushort*>(&h);
}
__device__ __forceinline__ float b2f(ushort u) {
    union { unsigned u; float f; } v; v.u = ((unsigned)u) << 16;
    return v.f;
}
// HW packed f32->fp8(e4m3): 4 floats -> 4 bytes in 2 VALU ops
__device__ __forceinline__ uint f2q4(float a, float b, float c, float d) {
    int r = __builtin_amdgcn_cvt_pk_fp8_f32(a, b, 0, false);
    r = __builtin_amdgcn_cvt_pk_fp8_f32(c, d, r, true);
    return (uint)r;
}
__device__ __forceinline__ bf16x8 as_b8(uint4 u) {
    union { uint4 u; bf16x8 b; } v; v.u = u; return v.b;
}
__device__ __forceinline__ bf16x8 as_b8_2(uint2 a, uint2 b) {
    return as_b8(make_uint4(a.x, a.y, b.x, b.y));
}
__device__ __forceinline__ float fexp2(float x) {
    return __builtin_amdgcn_exp2f(x);   // v_exp_f32: 2^x
}
union U2L { uint2 u; long l; };

// ---------------- workspace layout (float granularity offsets) ----------------
// Qt  : bf16 [B][N][32]   off 0          (wq pre-scaled by sqrt(log2 e))
// Vb  : fp8  [B][128][N]  off 524,288    (e4m3)
// RSI : f32  [B][N]       off 4,718,592  (stores 256/rowsum)
#define OFF_VB  524288
#define OFF_RSI 4718592

#define QSCALE 1.2011224087864498f   // sqrt(log2(e)); E comes out scaled by log2(e)

// K1: MFMA projection. Qt[b,n,d] (d<32, scaled), Vb[b,d,n] = fp8(wv.x + bv).
__global__ __launch_bounds__(256) void k_proj(const float* __restrict__ x,
        const float* __restrict__ wq, const float* __restrict__ wv,
        const float* __restrict__ bv, ushort* __restrict__ Qt, uchar* __restrict__ Vb) {
    __shared__ ushort Wl[160][136];
    __shared__ ushort Xs[64][136];   // [n][c] bf16
    int bid = (blockIdx.x & 7) * 64 + (blockIdx.x >> 3);   // XCD-chunked swizzle
    int b  = bid >> 5;
    int n0 = (bid & 31) << 6;
    int tid = threadIdx.x;
    #pragma unroll
    for (int k = 0; k < 20; ++k) {
        int idx = k * 256 + tid;
        int r = idx >> 5, c4 = (idx & 31) << 2;
        const float* srcw = (r < 32) ? (wq + r * 128 + c4) : (wv + (r - 32) * 128 + c4);
        float4 w4 = *(const float4*)srcw;
        float s = (r < 32) ? QSCALE : 1.0f;
        *(ushort4*)&Wl[r][c4] = make_ushort4(f2b(w4.x * s), f2b(w4.y * s),
                                             f2b(w4.z * s), f2b(w4.w * s));
    }
    const float* xb = x + (size_t)b * CC * NN;
    for (int idx = tid; idx < 2048; idx += 256) {
        int c = idx >> 4, n4 = (idx & 15) << 2;
        float4 xv = *(const float4*)&xb[c * NN + n0 + n4];
        Xs[n4][c]     = f2b(xv.x);
        Xs[n4 + 1][c] = f2b(xv.y);
        Xs[n4 + 2][c] = f2b(xv.z);
        Xs[n4 + 3][c] = f2b(xv.w);
    }
    __syncthreads();
    int w = tid >> 6, l = tid & 63, lr = l & 15, lg = l >> 4;
    f32x4 zero = {0.f, 0.f, 0.f, 0.f};
    int nn = n0 + w * 16 + lr;
    for (int dt = 0; dt < 10; ++dt) {
        f32x4 acc = zero;
        #pragma unroll
        for (int k = 0; k < 4; ++k) {
            bf16x8 a  = *(const bf16x8*)&Wl[dt * 16 + lr][k * 32 + lg * 8];
            bf16x8 bx = *(const bf16x8*)&Xs[w * 16 + lr][k * 32 + lg * 8];
            acc = __builtin_amdgcn_mfma_f32_16x16x32_bf16(a, bx, acc, 0, 0, 0);
        }
        if (dt < 2) {
            ushort4 p = make_ushort4(f2b(acc[0]), f2b(acc[1]), f2b(acc[2]), f2b(acc[3]));
            *(ushort4*)&Qt[(size_t)(b * NN + nn) * CQ + dt * 16 + lg * 4] = p;
        } else {
            union { uint u; uchar c[4]; } q;
            int vd = (dt - 2) * 16 + lg * 4;
            q.u = f2q4(acc[0] + bv[vd], acc[1] + bv[vd + 1],
                       acc[2] + bv[vd + 2], acc[3] + bv[vd + 3]);
            #pragma unroll
            for (int i = 0; i < 4; ++i)
                Vb[(size_t)(b * CC + vd + i) * NN + nn] = q.c[i];
        }
    }
}

// K2: row softmax denominators. RSI = 256/rowsum (fp8-W scaling folded in).
__global__ __launch_bounds__(512) void k_rowstats(const ushort* __restrict__ Qt,
        float* __restrict__ RSI) {
    __shared__ ushort Qm[128][36];
    __shared__ float Sred[2][64];
    int bid = (blockIdx.x & 7) * 64 + (blockIdx.x >> 3);
    int b  = bid >> 5;
    int n0 = (bid & 31) << 6;
    int tid = threadIdx.x;
    int w = tid >> 6, l = tid & 63, lr = l & 15, lg = l >> 4;
    int wn = w & 3, wm = w >> 2;
    const ushort* Qtb = Qt + (size_t)b * NN * CQ;
    bf16x8 aq = *(const bf16x8*)&Qtb[(size_t)(n0 + wn * 16 + lr) * CQ + lg * 8];
    int sr = tid >> 2, sc = (tid & 3) * 8;
    uint4 q0 = *(const uint4*)&Qtb[(size_t)sr * CQ + sc];
    float S[4] = {0.f, 0.f, 0.f, 0.f};
    f32x4 zero = {0.f, 0.f, 0.f, 0.f};
    for (int t = 0; t < 16; ++t) {
        __syncthreads();
        *(uint4*)&Qm[sr][sc] = q0;
        __syncthreads();
        if (t < 15)
            q0 = *(const uint4*)&Qtb[(size_t)((t + 1) * 128 + sr) * CQ + sc];
        #pragma unroll
        for (int mi = 0; mi < 4; ++mi) {
            bf16x8 bq = *(const bf16x8*)&Qm[(wm * 4 + mi) * 16 + lr][lg * 8];
            f32x4 e = __builtin_amdgcn_mfma_f32_16x16x32_bf16(aq, bq, zero, 0, 0, 0);
            S[0] += fexp2(e[0]); S[1] += fexp2(e[1]);
            S[2] += fexp2(e[2]); S[3] += fexp2(e[3]);
        }
    }
    #pragma unroll
    for (int d = 1; d < 16; d <<= 1) {
        #pragma unroll
        for (int i = 0; i < 4; ++i) S[i] += __shfl_xor(S[i], d);
    }
    if (lr == 0) {
        #pragma unroll
        for (int i = 0; i < 4; ++i) Sred[wm][wn * 16 + lg * 4 + i] = S[i];
    }
    __syncthreads();
    if (tid < 64)
        RSI[b * NN + n0 + tid] = 256.f / (Sred[0][tid] + Sred[1][tid]);
}

// K3: attn + PV + fused final. NT=128 (16 iters, 17 barriers), fp8 V/W, HW cvt.
// Producers (w 0-7): each owns n-strip [16w,16w+16) x all 128 m: 8 E-MFMA + softmax.
// Consumers (w 8-11): PV fp8 32x32x16, d-64 x m-64 quadrants, 8 kk per iter.
__global__ __launch_bounds__(768, 3) void k_attn_pv(const ushort* __restrict__ Qt,
        const uchar* __restrict__ Vb, const float* __restrict__ RSI,
        const float* __restrict__ x, const float* __restrict__ wt,
        const float* __restrict__ bt, const float* __restrict__ gamma,
        const float* __restrict__ beta, const float* __restrict__ bn_mean,
        const float* __restrict__ bn_var, float* __restrict__ out) {
    __shared__ uchar SMp[2][2][128][136];  // [V=0/W=1][buf][row][136B]; Us alias
    __shared__ ushort wtl[16896];          // wt bf16 [128][132]
    __shared__ float csred[8][128];
    __shared__ float csum[128];
    __shared__ float fAl[128], fBl[128];
    int bid = (blockIdx.x & 7) * 32 + (blockIdx.x >> 3);   // XCD-chunked swizzle
    int b  = bid >> 4;
    int m0 = (bid & 15) << 7;
    int tid = threadIdx.x;
    int w = tid >> 6, l = tid & 63, lr = l & 15, lg = l >> 4;
    const ushort* Qtb = Qt + (size_t)b * NN * CQ;
    const uchar*  Vbb = Vb + (size_t)b * CC * NN;
    const float*  RSb = RSI + (size_t)b * NN;
    const float*  xb  = x   + (size_t)b * CC * NN;
    float*        outb = out + (size_t)b * CC * NN;
    f32x4 zero = {0.f, 0.f, 0.f, 0.f};
    bool producer = (w < 8);

    // ---- stage wt -> wtl (bf16, stride 132) + BN constants ----
    for (int idx = tid; idx < 4096; idx += 768) {
        int r = idx >> 5, c4 = (idx & 31) << 2;
        float4 w4 = *(const float4*)&wt[r * 128 + c4];
        *(ushort4*)&wtl[r * 132 + c4] =
            make_ushort4(f2b(w4.x), f2b(w4.y), f2b(w4.z), f2b(w4.w));
    }
    if (tid < 128) {
        float A = gamma[tid] * rsqrtf(bn_var[tid] + 1e-5f);
        fAl[tid] = A;
        fBl[tid] = (bt[tid] - bn_mean[tid]) * A + beta[tid];
    }

    // ---------------- producer state ----------------
    int wn = w;                              // n-strip (0..7)
    bf16x8 bm[8];
    float cs[8] = {0.f, 0.f, 0.f, 0.f, 0.f, 0.f, 0.f, 0.f};
    int sv = 0, shv = 0;
    const uchar* vsrc = nullptr;
    bf16x8 aq_nx; float4 rsi_nx;
    // ---------------- consumer state ----------------
    int cw = w - 8;
    int dh = cw >> 1, mh2 = cw & 1;          // d-half, m-half
    int ar = l & 31, kh = l >> 5;
    f32x16 pacc00, pacc01, pacc10, pacc11;

    if (producer) {
        #pragma unroll
        for (int mi = 0; mi < 8; ++mi)
            bm[mi] = *(const bf16x8*)&Qtb[(size_t)(m0 + mi * 16 + lr) * CQ + lg * 8];
        sv = tid >> 2; shv = (tid & 3) * 32;   // V row, 32-byte chunk (2 uint4)
        vsrc = Vbb + (size_t)sv * NN + shv;
        // ---- stage V(0) -> buf 0 ----
        {
            uint4 v0 = *(const uint4*)(vsrc);
            uint4 v1 = *(const uint4*)(vsrc + 16);
            uchar* dst = &SMp[0][0][sv][shv];
            *(uint2*)(dst)      = make_uint2(v0.x, v0.y);
            *(uint2*)(dst + 8)  = make_uint2(v0.z, v0.w);
            *(uint2*)(dst + 16) = make_uint2(v1.x, v1.y);
            *(uint2*)(dst + 24) = make_uint2(v1.z, v1.w);
        }
        // ---- E(0) -> Ws buf 0 ----
        {
            bf16x8 aq0 = *(const bf16x8*)&Qtb[(size_t)(wn * 16 + lr) * CQ + lg * 8];
            float4 r4 = *(const float4*)&RSb[wn * 16 + lg * 4];
            int nb = wn * 16 + lg * 4;
            #pragma unroll
            for (int mi = 0; mi < 8; ++mi) {
                f32x4 e = __builtin_amdgcn_mfma_f32_16x16x32_bf16(aq0, bm[mi], zero, 0, 0, 0);
                float w0 = fexp2(e[0]) * r4.x;
                float w1 = fexp2(e[1]) * r4.y;
                float w2 = fexp2(e[2]) * r4.z;
                float w3 = fexp2(e[3]) * r4.w;
                cs[mi] += w0 + w1 + w2 + w3;
                *(uint*)&SMp[1][0][mi * 16 + lr][nb] = f2q4(w0, w1, w2, w3);
            }
        }
        aq_nx  = *(const bf16x8*)&Qtb[(size_t)(128 + wn * 16 + lr) * CQ + lg * 8];
        rsi_nx = *(const float4*)&RSb[128 + wn * 16 + lg * 4];
    } else {
        #pragma unroll
        for (int r = 0; r < 16; ++r) {
            pacc00[r] = 0.f; pacc01[r] = 0.f; pacc10[r] = 0.f; pacc11[r] = 0.f;
        }
    }
    __syncthreads();
    for (int t = 0; t < 16; ++t) {
        int cur = t & 1;
        if (producer) {
            if (t < 15) {
                int ntn = (t + 1) * 128;
                // issue V(t+1) global loads (in flight under E+exp)
                uint4 v0 = *(const uint4*)(vsrc + ntn);
                uint4 v1 = *(const uint4*)(vsrc + ntn + 16);
                bf16x8 aq = aq_nx;
                float4 r4 = rsi_nx;
                if (t < 14) {
                    int nt2 = (t + 2) * 128;
                    aq_nx  = *(const bf16x8*)&Qtb[(size_t)(nt2 + wn * 16 + lr) * CQ + lg * 8];
                    rsi_nx = *(const float4*)&RSb[nt2 + wn * 16 + lg * 4];
                }
                // ---- E(t+1) -> Ws buf cur^1 ----
                int nb = wn * 16 + lg * 4;
                #pragma unroll
                for (int mi = 0; mi < 8; ++mi) {
                    f32x4 e = __builtin_amdgcn_mfma_f32_16x16x32_bf16(aq, bm[mi], zero, 0, 0, 0);
                    float w0 = fexp2(e[0]) * r4.x;
                    float w1 = fexp2(e[1]) * r4.y;
                    float w2 = fexp2(e[2]) * r4.z;
                    float w3 = fexp2(e[3]) * r4.w;
                    cs[mi] += w0 + w1 + w2 + w3;
                    *(uint*)&SMp[1][cur ^ 1][mi * 16 + lr][nb] = f2q4(w0, w1, w2, w3);
                }
                // ---- write V(t+1) -> buf cur^1 ----
                uchar* dst = &SMp[0][cur ^ 1][sv][shv];
                *(uint2*)(dst)      = make_uint2(v0.x, v0.y);
                *(uint2*)(dst + 8)  = make_uint2(v0.z, v0.w);
                *(uint2*)(dst + 16) = make_uint2(v1.x, v1.y);
                *(uint2*)(dst + 24) = make_uint2(v1.z, v1.w);
            }
        } else {
            // ---- PV fp8 on tile t: wave owns d [dh*64,+64) x m [mh2*64,+64) ----
            __builtin_amdgcn_s_setprio(1);
            #pragma unroll
            for (int kk = 0; kk < 8; ++kk) {
                int cb = kk * 16 + kh * 8;    // column byte
                U2L va0, va1, wb0, wb1;
                va0.u = *(const uint2*)&SMp[0][cur][dh * 64 + ar][cb];
                va1.u = *(const uint2*)&SMp[0][cur][dh * 64 + 32 + ar][cb];
                wb0.u = *(const uint2*)&SMp[1][cur][mh2 * 64 + ar][cb];
                wb1.u = *(const uint2*)&SMp[1][cur][mh2 * 64 + 32 + ar][cb];
                pacc00 = __builtin_amdgcn_mfma_f32_32x32x16_fp8_fp8(va0.l, wb0.l, pacc00, 0, 0, 0);
                pacc01 = __builtin_amdgcn_mfma_f32_32x32x16_fp8_fp8(va0.l, wb1.l, pacc01, 0, 0, 0);
                pacc10 = __builtin_amdgcn_mfma_f32_32x32x16_fp8_fp8(va1.l, wb0.l, pacc10, 0, 0, 0);
                pacc11 = __builtin_amdgcn_mfma_f32_32x32x16_fp8_fp8(va1.l, wb1.l, pacc11, 0, 0, 0);
            }
            __builtin_amdgcn_s_setprio(0);
        }
        __syncthreads();
    }
    // ---- colsum reduce ----
    if (producer) {
        #pragma unroll
        for (int mi = 0; mi < 8; ++mi) {
            cs[mi] += __shfl_xor(cs[mi], 16);
            cs[mi] += __shfl_xor(cs[mi], 32);
        }
        if (lg == 0) {
            #pragma unroll
            for (int mi = 0; mi < 8; ++mi)
                csred[wn][mi * 16 + lr] = cs[mi];
        }
    }
    __syncthreads();
    if (tid < 128) {
        float tot = 0.f;
        #pragma unroll
        for (int w2 = 0; w2 < 8; ++w2) tot += csred[w2][tid];
        csum[tid] = 1.f / (2.56e-7f + tot);   // eps*256 (W scaled by 256)
    }
    __syncthreads();
    // ---- consumers: Us[m][c] = bf16(x - XR), alias on SMp, stride 132 ushorts ----
    ushort* UsP = (ushort*)&SMp[0][0][0][0];
    if (!producer) {
        float inv0 = csum[mh2 * 64 + ar];
        float inv1 = csum[mh2 * 64 + 32 + ar];
        int mA = m0 + mh2 * 64 + ar;          // global m
        int mL = mh2 * 64 + ar;               // local m
        #pragma unroll
        for (int g = 0; g < 4; ++g) {
            int db = dh * 64 + 8 * g + 4 * kh;   // 4 consecutive d at db..db+3
            ushort4 u00, u01, u10, u11;
            #pragma unroll
            for (int j = 0; j < 4; ++j) {
                int r = 4 * g + j;
                float x00 = xb[(size_t)(db + j) * NN + mA];
                float x01 = xb[(size_t)(db + j) * NN + mA + 32];
                float x10 = xb[(size_t)(db + 32 + j) * NN + mA];
                float x11 = xb[(size_t)(db + 32 + j) * NN + mA + 32];
                ((ushort*)&u00)[j] = f2b(x00 - pacc00[r] * inv0);
                ((ushort*)&u01)[j] = f2b(x01 - pacc01[r] * inv1);
                ((ushort*)&u10)[j] = f2b(x10 - pacc10[r] * inv0);
                ((ushort*)&u11)[j] = f2b(x11 - pacc11[r] * inv1);
            }
            *(ushort4*)&UsP[mL * 132 + db]             = u00;
            *(ushort4*)&UsP[(mL + 32) * 132 + db]      = u01;
            *(ushort4*)&UsP[mL * 132 + db + 32]        = u10;
            *(ushort4*)&UsP[(mL + 32) * 132 + db + 32] = u11;
        }
    }
    __syncthreads();
    // ---- all waves: t = wt @ Us^T; out = x + relu(t*fA + fB) ----
    for (int tile = w; tile < 16; tile += 12) {
        int rt = tile >> 2, mt = tile & 3;
        f32x16 acc;
        #pragma unroll
        for (int r = 0; r < 16; ++r) acc[r] = 0.f;
        #pragma unroll
        for (int kk = 0; kk < 8; ++kk) {
            const ushort* ap = &wtl[(rt * 32 + ar) * 132 + kk * 16 + kh * 8];
            uint2 a0 = *(const uint2*)ap; uint2 a1 = *(const uint2*)(ap + 4);
            const ushort* bp = &UsP[(mt * 32 + ar) * 132 + kk * 16 + kh * 8];
            uint2 b0 = *(const uint2*)bp; uint2 b1 = *(const uint2*)(bp + 4);
            acc = __builtin_amdgcn_mfma_f32_32x32x16_bf16(
                as_b8_2(a0, a1), as_b8_2(b0, b1), acc, 0, 0, 0);
        }
        int m = m0 + mt * 32 + ar;
        #pragma unroll
        for (int g = 0; g < 4; ++g) {
            #pragma unroll
            for (int j = 0; j < 4; ++j) {
                int r = rt * 32 + j + 8 * g + 4 * kh;
                float t = acc[4 * g + j] * fAl[r] + fBl[r];
                t = fmaxf(t, 0.f);
                outb[(size_t)r * NN + m] = xb[(size_t)r * NN + m] + t;
            }
        }
    }
}

extern "C" void kernel_launch(void* const* d_in, const int* in_sizes, int n_in,
                              void* d_out, int out_size, void* d_ws, size_t ws_size,
                              hipStream_t stream) {
    const float* x       = (const float*)d_in[0];
    const float* wq      = (const float*)d_in[1];
    const float* wv      = (const float*)d_in[2];
    const float* bv      = (const float*)d_in[3];
    const float* wt      = (const float*)d_in[4];
    const float* bt      = (const float*)d_in[5];
    const float* gamma   = (const float*)d_in[6];
    const float* beta    = (const float*)d_in[7];
    const float* bn_mean = (const float*)d_in[8];
    const float* bn_var  = (const float*)d_in[9];
    float* out = (float*)d_out;
    float* ws  = (float*)d_ws;

    ushort* Qt   = (ushort*)ws;
    uchar*  Vbp  = (uchar*)(ws + OFF_VB);
    float*  RSI  = ws + OFF_RSI;

    k_proj<<<BB * 32, 256, 0, stream>>>(x, wq, wv, bv, Qt, Vbp);
    k_rowstats<<<BB * 32, 512, 0, stream>>>(Qt, RSI);
    k_attn_pv<<<BB * 16, 768, 0, stream>>>(Qt, Vbp, RSI, x, wt, bt, gamma, beta,
                                           bn_mean, bn_var, out);
}

// Round 19
// 60.334 us; speedup vs baseline: 1.1798x; 1.1798x over previous
//
#include <hip/hip_runtime.h>
#include <hip/hip_bf16.h>
#include <math.h>

#define BB 16
#define CC 128
#define NN 2048
#define CQ 32   // C/4

typedef __attribute__((ext_vector_type(8))) short bf16x8;
typedef __attribute__((ext_vector_type(4))) float f32x4;
typedef __attribute__((ext_vector_type(16))) float f32x16;
typedef unsigned char uchar;

__device__ __forceinline__ ushort f2b(float f) {
    __hip_bfloat16 h = __float2bfloat16(f);
    return *reinterpret_cast<ushort*>(&h);
}
__device__ __forceinline__ float b2f(ushort u) {
    union { unsigned u; float f; } v; v.u = ((unsigned)u) << 16;
    return v.f;
}
// HW packed f32->fp8(e4m3): 4 floats -> 4 bytes in 2 VALU ops
__device__ __forceinline__ uint f2q4(float a, float b, float c, float d) {
    int r = __builtin_amdgcn_cvt_pk_fp8_f32(a, b, 0, false);
    r = __builtin_amdgcn_cvt_pk_fp8_f32(c, d, r, true);
    return (uint)r;
}
__device__ __forceinline__ bf16x8 as_b8(uint4 u) {
    union { uint4 u; bf16x8 b; } v; v.u = u; return v.b;
}
__device__ __forceinline__ bf16x8 as_b8_2(uint2 a, uint2 b) {
    return as_b8(make_uint4(a.x, a.y, b.x, b.y));
}
__device__ __forceinline__ float fexp2(float x) {
    return __builtin_amdgcn_exp2f(x);   // v_exp_f32: 2^x
}
union U2L { uint2 u; long l; };

// ---------------- workspace layout (float granularity offsets) ----------------
// Qt  : bf16 [B][N][32]   off 0          (wq pre-scaled by sqrt(log2 e))
// Vb  : fp8  [B][128][N]  off 524,288    (e4m3)
// RSI : f32  [B][N]       off 4,718,592  (stores 256/rowsum)
#define OFF_VB  524288
#define OFF_RSI 4718592

#define QSCALE 1.2011224087864498f   // sqrt(log2(e)); E comes out scaled by log2(e)

// K1: MFMA projection. Qt[b,n,d] (d<32, scaled), Vb[b,d,n] = fp8(wv.x + bv).
__global__ __launch_bounds__(256) void k_proj(const float* __restrict__ x,
        const float* __restrict__ wq, const float* __restrict__ wv,
        const float* __restrict__ bv, ushort* __restrict__ Qt, uchar* __restrict__ Vb) {
    __shared__ ushort Wl[160][136];
    __shared__ ushort Xs[64][136];   // [n][c] bf16
    int bid = (blockIdx.x & 7) * 64 + (blockIdx.x >> 3);   // XCD-chunked swizzle
    int b  = bid >> 5;
    int n0 = (bid & 31) << 6;
    int tid = threadIdx.x;
    #pragma unroll
    for (int k = 0; k < 20; ++k) {
        int idx = k * 256 + tid;
        int r = idx >> 5, c4 = (idx & 31) << 2;
        const float* srcw = (r < 32) ? (wq + r * 128 + c4) : (wv + (r - 32) * 128 + c4);
        float4 w4 = *(const float4*)srcw;
        float s = (r < 32) ? QSCALE : 1.0f;
        *(ushort4*)&Wl[r][c4] = make_ushort4(f2b(w4.x * s), f2b(w4.y * s),
                                             f2b(w4.z * s), f2b(w4.w * s));
    }
    const float* xb = x + (size_t)b * CC * NN;
    for (int idx = tid; idx < 2048; idx += 256) {
        int c = idx >> 4, n4 = (idx & 15) << 2;
        float4 xv = *(const float4*)&xb[c * NN + n0 + n4];
        Xs[n4][c]     = f2b(xv.x);
        Xs[n4 + 1][c] = f2b(xv.y);
        Xs[n4 + 2][c] = f2b(xv.z);
        Xs[n4 + 3][c] = f2b(xv.w);
    }
    __syncthreads();
    int w = tid >> 6, l = tid & 63, lr = l & 15, lg = l >> 4;
    f32x4 zero = {0.f, 0.f, 0.f, 0.f};
    int nn = n0 + w * 16 + lr;
    for (int dt = 0; dt < 10; ++dt) {
        f32x4 acc = zero;
        #pragma unroll
        for (int k = 0; k < 4; ++k) {
            bf16x8 a  = *(const bf16x8*)&Wl[dt * 16 + lr][k * 32 + lg * 8];
            bf16x8 bx = *(const bf16x8*)&Xs[w * 16 + lr][k * 32 + lg * 8];
            acc = __builtin_amdgcn_mfma_f32_16x16x32_bf16(a, bx, acc, 0, 0, 0);
        }
        if (dt < 2) {
            ushort4 p = make_ushort4(f2b(acc[0]), f2b(acc[1]), f2b(acc[2]), f2b(acc[3]));
            *(ushort4*)&Qt[(size_t)(b * NN + nn) * CQ + dt * 16 + lg * 4] = p;
        } else {
            union { uint u; uchar c[4]; } q;
            int vd = (dt - 2) * 16 + lg * 4;
            q.u = f2q4(acc[0] + bv[vd], acc[1] + bv[vd + 1],
                       acc[2] + bv[vd + 2], acc[3] + bv[vd + 3]);
            #pragma unroll
            for (int i = 0; i < 4; ++i)
                Vb[(size_t)(b * CC + vd + i) * NN + nn] = q.c[i];
        }
    }
}

// K2: row softmax denominators. RSI = 256/rowsum (fp8-W scaling folded in).
__global__ __launch_bounds__(512) void k_rowstats(const ushort* __restrict__ Qt,
        float* __restrict__ RSI) {
    __shared__ ushort Qm[128][36];
    __shared__ float Sred[2][64];
    int bid = (blockIdx.x & 7) * 64 + (blockIdx.x >> 3);
    int b  = bid >> 5;
    int n0 = (bid & 31) << 6;
    int tid = threadIdx.x;
    int w = tid >> 6, l = tid & 63, lr = l & 15, lg = l >> 4;
    int wn = w & 3, wm = w >> 2;
    const ushort* Qtb = Qt + (size_t)b * NN * CQ;
    bf16x8 aq = *(const bf16x8*)&Qtb[(size_t)(n0 + wn * 16 + lr) * CQ + lg * 8];
    int sr = tid >> 2, sc = (tid & 3) * 8;
    uint4 q0 = *(const uint4*)&Qtb[(size_t)sr * CQ + sc];
    float S[4] = {0.f, 0.f, 0.f, 0.f};
    f32x4 zero = {0.f, 0.f, 0.f, 0.f};
    for (int t = 0; t < 16; ++t) {
        __syncthreads();
        *(uint4*)&Qm[sr][sc] = q0;
        __syncthreads();
        if (t < 15)
            q0 = *(const uint4*)&Qtb[(size_t)((t + 1) * 128 + sr) * CQ + sc];
        #pragma unroll
        for (int mi = 0; mi < 4; ++mi) {
            bf16x8 bq = *(const bf16x8*)&Qm[(wm * 4 + mi) * 16 + lr][lg * 8];
            f32x4 e = __builtin_amdgcn_mfma_f32_16x16x32_bf16(aq, bq, zero, 0, 0, 0);
            S[0] += fexp2(e[0]); S[1] += fexp2(e[1]);
            S[2] += fexp2(e[2]); S[3] += fexp2(e[3]);
        }
    }
    #pragma unroll
    for (int d = 1; d < 16; d <<= 1) {
        #pragma unroll
        for (int i = 0; i < 4; ++i) S[i] += __shfl_xor(S[i], d);
    }
    if (lr == 0) {
        #pragma unroll
        for (int i = 0; i < 4; ++i) Sred[wm][wn * 16 + lg * 4 + i] = S[i];
    }
    __syncthreads();
    if (tid < 64)
        RSI[b * NN + n0 + tid] = 256.f / (Sred[0][tid] + Sred[1][tid]);
}

// K3: attn + PV + fused final. R17 base (NT=64, 33 barriers, fp8 V/W, HW cvt),
// REBALANCED: 4 producers (waves 0-3) + 8 consumers (waves 4-11).
// Producer wave w: n-strip [16w,+16) x all 128 m -> 8 E-MFMA + 32 exp2/iter.
// Consumer cw: d-32 strip (cw>>1) x m-64 half (cw&1) -> 8 fp8 MFMA + 12 reads.
__global__ __launch_bounds__(768, 3) void k_attn_pv(const ushort* __restrict__ Qt,
        const uchar* __restrict__ Vb, const float* __restrict__ RSI,
        const float* __restrict__ x, const float* __restrict__ wt,
        const float* __restrict__ bt, const float* __restrict__ gamma,
        const float* __restrict__ beta, const float* __restrict__ bn_mean,
        const float* __restrict__ bn_var, float* __restrict__ out) {
    __shared__ uchar SMp[2][2][128][72];  // [V=0/W=1][buf][row][72B]; Us alias
    __shared__ ushort wtl[16896];         // wt bf16 [128][132]
    __shared__ float csred[4][128];
    __shared__ float csum[128];
    __shared__ float fAl[128], fBl[128];
    int bid = (blockIdx.x & 7) * 32 + (blockIdx.x >> 3);   // XCD-chunked swizzle
    int b  = bid >> 4;
    int m0 = (bid & 15) << 7;
    int tid = threadIdx.x;
    int w = tid >> 6, l = tid & 63, lr = l & 15, lg = l >> 4;
    const ushort* Qtb = Qt + (size_t)b * NN * CQ;
    const uchar*  Vbb = Vb + (size_t)b * CC * NN;
    const float*  RSb = RSI + (size_t)b * NN;
    const float*  xb  = x   + (size_t)b * CC * NN;
    float*        outb = out + (size_t)b * CC * NN;
    f32x4 zero = {0.f, 0.f, 0.f, 0.f};
    bool producer = (w < 4);

    // ---- stage wt -> wtl (bf16, stride 132) + BN constants ----
    for (int idx = tid; idx < 4096; idx += 768) {
        int r = idx >> 5, c4 = (idx & 31) << 2;
        float4 w4 = *(const float4*)&wt[r * 128 + c4];
        *(ushort4*)&wtl[r * 132 + c4] =
            make_ushort4(f2b(w4.x), f2b(w4.y), f2b(w4.z), f2b(w4.w));
    }
    if (tid < 128) {
        float A = gamma[tid] * rsqrtf(bn_var[tid] + 1e-5f);
        fAl[tid] = A;
        fBl[tid] = (bt[tid] - bn_mean[tid]) * A + beta[tid];
    }

    // ---------------- producer state (waves 0-3) ----------------
    int wn = w;                              // n-strip 0..3
    bf16x8 bm[8];
    float cs[8] = {0.f, 0.f, 0.f, 0.f, 0.f, 0.f, 0.f, 0.f};
    int sv = 0, shv = 0;
    const uchar* vsrc = nullptr;
    bf16x8 aq_nx; float4 rsi_nx;
    // ---------------- consumer state (waves 4-11) ----------------
    int cw = w - 4;
    int dq = cw >> 1, mh2 = cw & 1;          // d-32 strip, m-half
    int ar = l & 31, kh = l >> 5;
    f32x16 pacc0, pacc1;

    if (producer) {
        #pragma unroll
        for (int mi = 0; mi < 8; ++mi)
            bm[mi] = *(const bf16x8*)&Qtb[(size_t)(m0 + mi * 16 + lr) * CQ + lg * 8];
        sv = tid >> 1; shv = (tid & 1) * 32;   // V row (0..127), 32-byte half
        vsrc = Vbb + (size_t)sv * NN + shv;
        // ---- stage V(0) -> buf 0 ----
        {
            uint4 v0 = *(const uint4*)(vsrc);
            uint4 v1 = *(const uint4*)(vsrc + 16);
            uchar* dst = &SMp[0][0][sv][shv];
            *(uint2*)(dst)      = make_uint2(v0.x, v0.y);
            *(uint2*)(dst + 8)  = make_uint2(v0.z, v0.w);
            *(uint2*)(dst + 16) = make_uint2(v1.x, v1.y);
            *(uint2*)(dst + 24) = make_uint2(v1.z, v1.w);
        }
        // ---- E(0) -> Ws buf 0 ----
        {
            bf16x8 aq0 = *(const bf16x8*)&Qtb[(size_t)(wn * 16 + lr) * CQ + lg * 8];
            float4 r4 = *(const float4*)&RSb[wn * 16 + lg * 4];
            int nb = wn * 16 + lg * 4;
            #pragma unroll
            for (int mi = 0; mi < 8; ++mi) {
                f32x4 e = __builtin_amdgcn_mfma_f32_16x16x32_bf16(aq0, bm[mi], zero, 0, 0, 0);
                float w0 = fexp2(e[0]) * r4.x;
                float w1 = fexp2(e[1]) * r4.y;
                float w2 = fexp2(e[2]) * r4.z;
                float w3 = fexp2(e[3]) * r4.w;
                cs[mi] += w0 + w1 + w2 + w3;
                *(uint*)&SMp[1][0][mi * 16 + lr][nb] = f2q4(w0, w1, w2, w3);
            }
        }
        aq_nx  = *(const bf16x8*)&Qtb[(size_t)(64 + wn * 16 + lr) * CQ + lg * 8];
        rsi_nx = *(const float4*)&RSb[64 + wn * 16 + lg * 4];
    } else {
        #pragma unroll
        for (int r = 0; r < 16; ++r) { pacc0[r] = 0.f; pacc1[r] = 0.f; }
    }
    __syncthreads();
    for (int t = 0; t < 32; ++t) {
        int cur = t & 1;
        if (producer) {
            if (t < 31) {
                int ntn = (t + 1) * 64;
                // issue V(t+1) global loads (in flight under E+exp)
                uint4 v0 = *(const uint4*)(vsrc + ntn);
                uint4 v1 = *(const uint4*)(vsrc + ntn + 16);
                bf16x8 aq = aq_nx;
                float4 r4 = rsi_nx;
                if (t < 30) {
                    int nt2 = (t + 2) * 64;
                    aq_nx  = *(const bf16x8*)&Qtb[(size_t)(nt2 + wn * 16 + lr) * CQ + lg * 8];
                    rsi_nx = *(const float4*)&RSb[nt2 + wn * 16 + lg * 4];
                }
                // ---- E(t+1) -> Ws buf cur^1 ----
                int nb = wn * 16 + lg * 4;
                #pragma unroll
                for (int mi = 0; mi < 8; ++mi) {
                    f32x4 e = __builtin_amdgcn_mfma_f32_16x16x32_bf16(aq, bm[mi], zero, 0, 0, 0);
                    float w0 = fexp2(e[0]) * r4.x;
                    float w1 = fexp2(e[1]) * r4.y;
                    float w2 = fexp2(e[2]) * r4.z;
                    float w3 = fexp2(e[3]) * r4.w;
                    cs[mi] += w0 + w1 + w2 + w3;
                    *(uint*)&SMp[1][cur ^ 1][mi * 16 + lr][nb] = f2q4(w0, w1, w2, w3);
                }
                // ---- write V(t+1) -> buf cur^1 ----
                uchar* dst = &SMp[0][cur ^ 1][sv][shv];
                *(uint2*)(dst)      = make_uint2(v0.x, v0.y);
                *(uint2*)(dst + 8)  = make_uint2(v0.z, v0.w);
                *(uint2*)(dst + 16) = make_uint2(v1.x, v1.y);
                *(uint2*)(dst + 24) = make_uint2(v1.z, v1.w);
            }
        } else {
            // ---- PV fp8: consumer owns d [32dq,+32) x m [64mh2,+64) ----
            __builtin_amdgcn_s_setprio(1);
            #pragma unroll
            for (int kk = 0; kk < 4; ++kk) {
                int cb = kk * 16 + kh * 8;    // column byte
                U2L va, wb0, wb1;
                va.u  = *(const uint2*)&SMp[0][cur][dq * 32 + ar][cb];
                wb0.u = *(const uint2*)&SMp[1][cur][mh2 * 64 + ar][cb];
                wb1.u = *(const uint2*)&SMp[1][cur][mh2 * 64 + 32 + ar][cb];
                pacc0 = __builtin_amdgcn_mfma_f32_32x32x16_fp8_fp8(va.l, wb0.l, pacc0, 0, 0, 0);
                pacc1 = __builtin_amdgcn_mfma_f32_32x32x16_fp8_fp8(va.l, wb1.l, pacc1, 0, 0, 0);
            }
            __builtin_amdgcn_s_setprio(0);
        }
        __syncthreads();
    }
    // ---- colsum reduce (4 producer waves hold cs[8]) ----
    if (producer) {
        #pragma unroll
        for (int mi = 0; mi < 8; ++mi) {
            cs[mi] += __shfl_xor(cs[mi], 16);
            cs[mi] += __shfl_xor(cs[mi], 32);
        }
        if (lg == 0) {
            #pragma unroll
            for (int mi = 0; mi < 8; ++mi)
                csred[wn][mi * 16 + lr] = cs[mi];
        }
    }
    __syncthreads();
    if (tid < 128) {
        float tot = csred[0][tid] + csred[1][tid] + csred[2][tid] + csred[3][tid];
        csum[tid] = 1.f / (2.56e-7f + tot);   // eps*256 (W scaled by 256)
    }
    __syncthreads();
    // ---- consumers: Us[m][c] = bf16(x - XR), alias on SMp, stride 132 ushorts ----
    ushort* UsP = (ushort*)&SMp[0][0][0][0];
    if (!producer) {
        float inv0 = csum[mh2 * 64 + ar];
        float inv1 = csum[mh2 * 64 + 32 + ar];
        int mA = m0 + mh2 * 64 + ar;          // global m
        int mL = mh2 * 64 + ar;               // local m
        #pragma unroll
        for (int g = 0; g < 4; ++g) {
            int db = dq * 32 + 8 * g + 4 * kh;   // 4 consecutive d at db..db+3
            ushort4 u0, u1;
            #pragma unroll
            for (int j = 0; j < 4; ++j) {
                int r = 4 * g + j;
                float x0 = xb[(size_t)(db + j) * NN + mA];
                float x1 = xb[(size_t)(db + j) * NN + mA + 32];
                ((ushort*)&u0)[j] = f2b(x0 - pacc0[r] * inv0);
                ((ushort*)&u1)[j] = f2b(x1 - pacc1[r] * inv1);
            }
            *(ushort4*)&UsP[mL * 132 + db]        = u0;
            *(ushort4*)&UsP[(mL + 32) * 132 + db] = u1;
        }
    }
    __syncthreads();
    // ---- all waves: t = wt @ Us^T; out = x + relu(t*fA + fB) ----
    for (int tile = w; tile < 16; tile += 12) {
        int rt = tile >> 2, mt = tile & 3;
        f32x16 acc;
        #pragma unroll
        for (int r = 0; r < 16; ++r) acc[r] = 0.f;
        #pragma unroll
        for (int kk = 0; kk < 8; ++kk) {
            const ushort* ap = &wtl[(rt * 32 + ar) * 132 + kk * 16 + kh * 8];
            uint2 a0 = *(const uint2*)ap; uint2 a1 = *(const uint2*)(ap + 4);
            const ushort* bp = &UsP[(mt * 32 + ar) * 132 + kk * 16 + kh * 8];
            uint2 b0 = *(const uint2*)bp; uint2 b1 = *(const uint2*)(bp + 4);
            acc = __builtin_amdgcn_mfma_f32_32x32x16_bf16(
                as_b8_2(a0, a1), as_b8_2(b0, b1), acc, 0, 0, 0);
        }
        int m = m0 + mt * 32 + ar;
        #pragma unroll
        for (int g = 0; g < 4; ++g) {
            #pragma unroll
            for (int j = 0; j < 4; ++j) {
                int r = rt * 32 + j + 8 * g + 4 * kh;
                float t = acc[4 * g + j] * fAl[r] + fBl[r];
                t = fmaxf(t, 0.f);
                outb[(size_t)r * NN + m] = xb[(size_t)r * NN + m] + t;
            }
        }
    }
}

extern "C" void kernel_launch(void* const* d_in, const int* in_sizes, int n_in,
                              void* d_out, int out_size, void* d_ws, size_t ws_size,
                              hipStream_t stream) {
    const float* x       = (const float*)d_in[0];
    const float* wq      = (const float*)d_in[1];
    const float* wv      = (const float*)d_in[2];
    const float* bv      = (const float*)d_in[3];
    const float* wt      = (const float*)d_in[4];
    const float* bt      = (const float*)d_in[5];
    const float* gamma   = (const float*)d_in[6];
    const float* beta    = (const float*)d_in[7];
    const float* bn_mean = (const float*)d_in[8];
    const float* bn_var  = (const float*)d_in[9];
    float* out = (float*)d_out;
    float* ws  = (float*)d_ws;

    ushort* Qt   = (ushort*)ws;
    uchar*  Vbp  = (uchar*)(ws + OFF_VB);
    float*  RSI  = ws + OFF_RSI;

    k_proj<<<BB * 32, 256, 0, stream>>>(x, wq, wv, bv, Qt, Vbp);
    k_rowstats<<<BB * 32, 512, 0, stream>>>(Qt, RSI);
    k_attn_pv<<<BB * 16, 768, 0, stream>>>(Qt, Vbp, RSI, x, wt, bt, gamma, beta,
                                           bn_mean, bn_var, out);
}

// Round 20
// 56.397 us; speedup vs baseline: 1.2622x; 1.0698x over previous
//
#include <hip/hip_runtime.h>
#include <hip/hip_bf16.h>
#include <math.h>

#define BB 16
#define CC 128
#define NN 2048
#define CQ 32   // C/4

typedef __attribute__((ext_vector_type(8))) short bf16x8;
typedef __attribute__((ext_vector_type(4))) float f32x4;
typedef __attribute__((ext_vector_type(16))) float f32x16;
typedef unsigned char uchar;

__device__ __forceinline__ ushort f2b(float f) {
    __hip_bfloat16 h = __float2bfloat16(f);
    return *reinterpret_cast<ushort*>(&h);
}
__device__ __forceinline__ float b2f(ushort u) {
    union { unsigned u; float f; } v; v.u = ((unsigned)u) << 16;
    return v.f;
}
// HW packed f32->fp8(e4m3): 4 floats -> 4 bytes in 2 VALU ops
__device__ __forceinline__ uint f2q4(float a, float b, float c, float d) {
    int r = __builtin_amdgcn_cvt_pk_fp8_f32(a, b, 0, false);
    r = __builtin_amdgcn_cvt_pk_fp8_f32(c, d, r, true);
    return (uint)r;
}
__device__ __forceinline__ bf16x8 as_b8(uint4 u) {
    union { uint4 u; bf16x8 b; } v; v.u = u; return v.b;
}
__device__ __forceinline__ bf16x8 as_b8_2(uint2 a, uint2 b) {
    return as_b8(make_uint4(a.x, a.y, b.x, b.y));
}
__device__ __forceinline__ float fexp2(float x) {
    return __builtin_amdgcn_exp2f(x);   // v_exp_f32: 2^x
}
union U2L { uint2 u; long l; };

// ---------------- workspace layout (float granularity offsets) ----------------
// Qt  : bf16 [B][N][32]   off 0          (wq pre-scaled by sqrt(log2 e))
// Vb  : fp8  [B][128][N]  off 524,288    (e4m3)
// RSI : f32  [B][N]       off 4,718,592  (stores 256/rowsum)
#define OFF_VB  524288
#define OFF_RSI 4718592

#define QSCALE 1.2011224087864498f   // sqrt(log2(e)); E comes out scaled by log2(e)

// K1: MFMA projection. Qt[b,n,d] (d<32, scaled), Vb[b,d,n] = fp8(wv.x + bv).
__global__ __launch_bounds__(256) void k_proj(const float* __restrict__ x,
        const float* __restrict__ wq, const float* __restrict__ wv,
        const float* __restrict__ bv, ushort* __restrict__ Qt, uchar* __restrict__ Vb) {
    __shared__ ushort Wl[160][136];
    __shared__ ushort Xs[64][136];   // [n][c] bf16
    int bid = (blockIdx.x & 7) * 64 + (blockIdx.x >> 3);   // XCD-chunked swizzle
    int b  = bid >> 5;
    int n0 = (bid & 31) << 6;
    int tid = threadIdx.x;
    #pragma unroll
    for (int k = 0; k < 20; ++k) {
        int idx = k * 256 + tid;
        int r = idx >> 5, c4 = (idx & 31) << 2;
        const float* srcw = (r < 32) ? (wq + r * 128 + c4) : (wv + (r - 32) * 128 + c4);
        float4 w4 = *(const float4*)srcw;
        float s = (r < 32) ? QSCALE : 1.0f;
        *(ushort4*)&Wl[r][c4] = make_ushort4(f2b(w4.x * s), f2b(w4.y * s),
                                             f2b(w4.z * s), f2b(w4.w * s));
    }
    const float* xb = x + (size_t)b * CC * NN;
    for (int idx = tid; idx < 2048; idx += 256) {
        int c = idx >> 4, n4 = (idx & 15) << 2;
        float4 xv = *(const float4*)&xb[c * NN + n0 + n4];
        Xs[n4][c]     = f2b(xv.x);
        Xs[n4 + 1][c] = f2b(xv.y);
        Xs[n4 + 2][c] = f2b(xv.z);
        Xs[n4 + 3][c] = f2b(xv.w);
    }
    __syncthreads();
    int w = tid >> 6, l = tid & 63, lr = l & 15, lg = l >> 4;
    f32x4 zero = {0.f, 0.f, 0.f, 0.f};
    int nn = n0 + w * 16 + lr;
    for (int dt = 0; dt < 10; ++dt) {
        f32x4 acc = zero;
        #pragma unroll
        for (int k = 0; k < 4; ++k) {
            bf16x8 a  = *(const bf16x8*)&Wl[dt * 16 + lr][k * 32 + lg * 8];
            bf16x8 bx = *(const bf16x8*)&Xs[w * 16 + lr][k * 32 + lg * 8];
            acc = __builtin_amdgcn_mfma_f32_16x16x32_bf16(a, bx, acc, 0, 0, 0);
        }
        if (dt < 2) {
            ushort4 p = make_ushort4(f2b(acc[0]), f2b(acc[1]), f2b(acc[2]), f2b(acc[3]));
            *(ushort4*)&Qt[(size_t)(b * NN + nn) * CQ + dt * 16 + lg * 4] = p;
        } else {
            union { uint u; uchar c[4]; } q;
            int vd = (dt - 2) * 16 + lg * 4;
            q.u = f2q4(acc[0] + bv[vd], acc[1] + bv[vd + 1],
                       acc[2] + bv[vd + 2], acc[3] + bv[vd + 3]);
            #pragma unroll
            for (int i = 0; i < 4; ++i)
                Vb[(size_t)(b * CC + vd + i) * NN + nn] = q.c[i];
        }
    }
}

// K2: row softmax denominators. RSI = 256/rowsum (fp8-W scaling folded in).
__global__ __launch_bounds__(512) void k_rowstats(const ushort* __restrict__ Qt,
        float* __restrict__ RSI) {
    __shared__ ushort Qm[128][36];
    __shared__ float Sred[2][64];
    int bid = (blockIdx.x & 7) * 64 + (blockIdx.x >> 3);
    int b  = bid >> 5;
    int n0 = (bid & 31) << 6;
    int tid = threadIdx.x;
    int w = tid >> 6, l = tid & 63, lr = l & 15, lg = l >> 4;
    int wn = w & 3, wm = w >> 2;
    const ushort* Qtb = Qt + (size_t)b * NN * CQ;
    bf16x8 aq = *(const bf16x8*)&Qtb[(size_t)(n0 + wn * 16 + lr) * CQ + lg * 8];
    int sr = tid >> 2, sc = (tid & 3) * 8;
    uint4 q0 = *(const uint4*)&Qtb[(size_t)sr * CQ + sc];
    float S[4] = {0.f, 0.f, 0.f, 0.f};
    f32x4 zero = {0.f, 0.f, 0.f, 0.f};
    for (int t = 0; t < 16; ++t) {
        __syncthreads();
        *(uint4*)&Qm[sr][sc] = q0;
        __syncthreads();
        if (t < 15)
            q0 = *(const uint4*)&Qtb[(size_t)((t + 1) * 128 + sr) * CQ + sc];
        #pragma unroll
        for (int mi = 0; mi < 4; ++mi) {
            bf16x8 bq = *(const bf16x8*)&Qm[(wm * 4 + mi) * 16 + lr][lg * 8];
            f32x4 e = __builtin_amdgcn_mfma_f32_16x16x32_bf16(aq, bq, zero, 0, 0, 0);
            S[0] += fexp2(e[0]); S[1] += fexp2(e[1]);
            S[2] += fexp2(e[2]); S[3] += fexp2(e[3]);
        }
    }
    #pragma unroll
    for (int d = 1; d < 16; d <<= 1) {
        #pragma unroll
        for (int i = 0; i < 4; ++i) S[i] += __shfl_xor(S[i], d);
    }
    if (lr == 0) {
        #pragma unroll
        for (int i = 0; i < 4; ++i) Sred[wm][wn * 16 + lg * 4 + i] = S[i];
    }
    __syncthreads();
    if (tid < 64)
        RSI[b * NN + n0 + tid] = 256.f / (Sred[0][tid] + Sred[1][tid]);
}

// K3: attn + PV + fused final. R17 phases, 1024 threads: 8 producers + 8 consumers.
// Producer w (0-7): n-strip w&3 x m-half w>>2 -> 4 E-MFMA + 16 exp2/iter (R17 body).
// Consumer cw (0-7): d-32 strip (cw>>1) x m-64 half (cw&1) -> 8 fp8 MFMA + 12 reads.
__global__ __launch_bounds__(1024, 4) void k_attn_pv(const ushort* __restrict__ Qt,
        const uchar* __restrict__ Vb, const float* __restrict__ RSI,
        const float* __restrict__ x, const float* __restrict__ wt,
        const float* __restrict__ bt, const float* __restrict__ gamma,
        const float* __restrict__ beta, const float* __restrict__ bn_mean,
        const float* __restrict__ bn_var, float* __restrict__ out) {
    __shared__ uchar SMp[2][2][128][72];  // [V=0/W=1][buf][row][72B]; Us alias
    __shared__ ushort wtl[16896];         // wt bf16 [128][132]
    __shared__ float csred[4][128];
    __shared__ float csum[128];
    __shared__ float fAl[128], fBl[128];
    int bid = (blockIdx.x & 7) * 32 + (blockIdx.x >> 3);   // XCD-chunked swizzle
    int b  = bid >> 4;
    int m0 = (bid & 15) << 7;
    int tid = threadIdx.x;
    int w = tid >> 6, l = tid & 63, lr = l & 15, lg = l >> 4;
    const ushort* Qtb = Qt + (size_t)b * NN * CQ;
    const uchar*  Vbb = Vb + (size_t)b * CC * NN;
    const float*  RSb = RSI + (size_t)b * NN;
    const float*  xb  = x   + (size_t)b * CC * NN;
    float*        outb = out + (size_t)b * CC * NN;
    f32x4 zero = {0.f, 0.f, 0.f, 0.f};
    bool producer = (w < 8);

    // ---- stage wt -> wtl (bf16, stride 132) + BN constants ----
    for (int idx = tid; idx < 4096; idx += 1024) {
        int r = idx >> 5, c4 = (idx & 31) << 2;
        float4 w4 = *(const float4*)&wt[r * 128 + c4];
        *(ushort4*)&wtl[r * 132 + c4] =
            make_ushort4(f2b(w4.x), f2b(w4.y), f2b(w4.z), f2b(w4.w));
    }
    if (tid < 128) {
        float A = gamma[tid] * rsqrtf(bn_var[tid] + 1e-5f);
        fAl[tid] = A;
        fBl[tid] = (bt[tid] - bn_mean[tid]) * A + beta[tid];
    }

    // ---------------- producer state (waves 0-7, R17 body) ----------------
    int wn = w & 3, mh = w >> 2;            // n-strip, m-half
    bf16x8 bm[4];
    float cs[4] = {0.f, 0.f, 0.f, 0.f};
    int sv = 0, shv = 0;
    const uchar* vsrc = nullptr;
    bf16x8 aq_nx; float4 rsi_nx;
    // ---------------- consumer state (waves 8-15) ----------------
    int cw = w - 8;
    int dq = cw >> 1, mh2 = cw & 1;         // d-32 strip, m-half
    int ar = l & 31, kh = l >> 5;
    f32x16 pacc0, pacc1;

    if (producer) {
        #pragma unroll
        for (int mi = 0; mi < 4; ++mi)
            bm[mi] = *(const bf16x8*)&Qtb[(size_t)(m0 + (mh * 4 + mi) * 16 + lr) * CQ + lg * 8];
        sv = tid >> 2; shv = (tid & 3) * 16;   // V row, 16-byte chunk
        vsrc = Vbb + (size_t)sv * NN + shv;
        {
            uint4 v0 = *(const uint4*)(vsrc);
            uchar* dst = &SMp[0][0][sv][shv];
            *(uint2*)(dst)     = make_uint2(v0.x, v0.y);
            *(uint2*)(dst + 8) = make_uint2(v0.z, v0.w);
        }
        {
            bf16x8 aq0 = *(const bf16x8*)&Qtb[(size_t)(wn * 16 + lr) * CQ + lg * 8];
            float4 r4 = *(const float4*)&RSb[wn * 16 + lg * 4];
            int nb = wn * 16 + lg * 4;   // byte offset (1B/elem)
            #pragma unroll
            for (int mi = 0; mi < 4; ++mi) {
                f32x4 e = __builtin_amdgcn_mfma_f32_16x16x32_bf16(aq0, bm[mi], zero, 0, 0, 0);
                float w0 = fexp2(e[0]) * r4.x;
                float w1 = fexp2(e[1]) * r4.y;
                float w2 = fexp2(e[2]) * r4.z;
                float w3 = fexp2(e[3]) * r4.w;
                cs[mi] += w0 + w1 + w2 + w3;
                *(uint*)&SMp[1][0][(mh * 4 + mi) * 16 + lr][nb] = f2q4(w0, w1, w2, w3);
            }
        }
        aq_nx  = *(const bf16x8*)&Qtb[(size_t)(64 + wn * 16 + lr) * CQ + lg * 8];
        rsi_nx = *(const float4*)&RSb[64 + wn * 16 + lg * 4];
    } else {
        #pragma unroll
        for (int r = 0; r < 16; ++r) { pacc0[r] = 0.f; pacc1[r] = 0.f; }
    }
    __syncthreads();
    for (int t = 0; t < 32; ++t) {
        int cur = t & 1;
        if (producer) {
            if (t < 31) {
                int ntn = (t + 1) * 64;
                uint4 v0 = *(const uint4*)(vsrc + ntn);
                bf16x8 aq = aq_nx;
                float4 r4 = rsi_nx;
                if (t < 30) {
                    int nt2 = (t + 2) * 64;
                    aq_nx  = *(const bf16x8*)&Qtb[(size_t)(nt2 + wn * 16 + lr) * CQ + lg * 8];
                    rsi_nx = *(const float4*)&RSb[nt2 + wn * 16 + lg * 4];
                }
                int nb = wn * 16 + lg * 4;
                #pragma unroll
                for (int mi = 0; mi < 4; ++mi) {
                    f32x4 e = __builtin_amdgcn_mfma_f32_16x16x32_bf16(aq, bm[mi], zero, 0, 0, 0);
                    float w0 = fexp2(e[0]) * r4.x;
                    float w1 = fexp2(e[1]) * r4.y;
                    float w2 = fexp2(e[2]) * r4.z;
                    float w3 = fexp2(e[3]) * r4.w;
                    cs[mi] += w0 + w1 + w2 + w3;
                    *(uint*)&SMp[1][cur ^ 1][(mh * 4 + mi) * 16 + lr][nb] =
                        f2q4(w0, w1, w2, w3);
                }
                uchar* dst = &SMp[0][cur ^ 1][sv][shv];
                *(uint2*)(dst)     = make_uint2(v0.x, v0.y);
                *(uint2*)(dst + 8) = make_uint2(v0.z, v0.w);
            }
        } else {
            // ---- PV fp8: consumer owns d [32dq,+32) x m [64mh2,+64) ----
            __builtin_amdgcn_s_setprio(1);
            #pragma unroll
            for (int kk = 0; kk < 4; ++kk) {
                int cb = kk * 16 + kh * 8;    // column byte
                U2L va, wb0, wb1;
                va.u  = *(const uint2*)&SMp[0][cur][dq * 32 + ar][cb];
                wb0.u = *(const uint2*)&SMp[1][cur][mh2 * 64 + ar][cb];
                wb1.u = *(const uint2*)&SMp[1][cur][mh2 * 64 + 32 + ar][cb];
                pacc0 = __builtin_amdgcn_mfma_f32_32x32x16_fp8_fp8(va.l, wb0.l, pacc0, 0, 0, 0);
                pacc1 = __builtin_amdgcn_mfma_f32_32x32x16_fp8_fp8(va.l, wb1.l, pacc1, 0, 0, 0);
            }
            __builtin_amdgcn_s_setprio(0);
        }
        __syncthreads();
    }
    // ---- colsum reduce (8 producer waves hold cs[4], R17 mapping) ----
    if (producer) {
        #pragma unroll
        for (int mi = 0; mi < 4; ++mi) {
            cs[mi] += __shfl_xor(cs[mi], 16);
            cs[mi] += __shfl_xor(cs[mi], 32);
        }
        if (lg == 0) {
            #pragma unroll
            for (int mi = 0; mi < 4; ++mi)
                csred[wn][(mh * 4 + mi) * 16 + lr] = cs[mi];
        }
    }
    __syncthreads();
    if (tid < 128) {
        float tot = csred[0][tid] + csred[1][tid] + csred[2][tid] + csred[3][tid];
        csum[tid] = 1.f / (2.56e-7f + tot);   // eps*256 (W scaled by 256)
    }
    __syncthreads();
    // ---- consumers: Us[m][c] = bf16(x - XR), alias on SMp, stride 132 ushorts ----
    ushort* UsP = (ushort*)&SMp[0][0][0][0];
    if (!producer) {
        float inv0 = csum[mh2 * 64 + ar];
        float inv1 = csum[mh2 * 64 + 32 + ar];
        int mA = m0 + mh2 * 64 + ar;          // global m
        int mL = mh2 * 64 + ar;               // local m
        #pragma unroll
        for (int g = 0; g < 4; ++g) {
            int db = dq * 32 + 8 * g + 4 * kh;   // 4 consecutive d at db..db+3
            ushort4 u0, u1;
            #pragma unroll
            for (int j = 0; j < 4; ++j) {
                int r = 4 * g + j;
                float x0 = xb[(size_t)(db + j) * NN + mA];
                float x1 = xb[(size_t)(db + j) * NN + mA + 32];
                ((ushort*)&u0)[j] = f2b(x0 - pacc0[r] * inv0);
                ((ushort*)&u1)[j] = f2b(x1 - pacc1[r] * inv1);
            }
            *(ushort4*)&UsP[mL * 132 + db]        = u0;
            *(ushort4*)&UsP[(mL + 32) * 132 + db] = u1;
        }
    }
    __syncthreads();
    // ---- all waves: t = wt @ Us^T; out = x + relu(t*fA + fB); 1 tile/wave ----
    {
        int tile = w;
        int rt = tile >> 2, mt = tile & 3;
        f32x16 acc;
        #pragma unroll
        for (int r = 0; r < 16; ++r) acc[r] = 0.f;
        #pragma unroll
        for (int kk = 0; kk < 8; ++kk) {
            const ushort* ap = &wtl[(rt * 32 + ar) * 132 + kk * 16 + kh * 8];
            uint2 a0 = *(const uint2*)ap; uint2 a1 = *(const uint2*)(ap + 4);
            const ushort* bp = &UsP[(mt * 32 + ar) * 132 + kk * 16 + kh * 8];
            uint2 b0 = *(const uint2*)bp; uint2 b1 = *(const uint2*)(bp + 4);
            acc = __builtin_amdgcn_mfma_f32_32x32x16_bf16(
                as_b8_2(a0, a1), as_b8_2(b0, b1), acc, 0, 0, 0);
        }
        int m = m0 + mt * 32 + ar;
        #pragma unroll
        for (int g = 0; g < 4; ++g) {
            #pragma unroll
            for (int j = 0; j < 4; ++j) {
                int r = rt * 32 + j + 8 * g + 4 * kh;
                float t = acc[4 * g + j] * fAl[r] + fBl[r];
                t = fmaxf(t, 0.f);
                outb[(size_t)r * NN + m] = xb[(size_t)r * NN + m] + t;
            }
        }
    }
}

extern "C" void kernel_launch(void* const* d_in, const int* in_sizes, int n_in,
                              void* d_out, int out_size, void* d_ws, size_t ws_size,
                              hipStream_t stream) {
    const float* x       = (const float*)d_in[0];
    const float* wq      = (const float*)d_in[1];
    const float* wv      = (const float*)d_in[2];
    const float* bv      = (const float*)d_in[3];
    const float* wt      = (const float*)d_in[4];
    const float* bt      = (const float*)d_in[5];
    const float* gamma   = (const float*)d_in[6];
    const float* beta    = (const float*)d_in[7];
    const float* bn_mean = (const float*)d_in[8];
    const float* bn_var  = (const float*)d_in[9];
    float* out = (float*)d_out;
    float* ws  = (float*)d_ws;

    ushort* Qt   = (ushort*)ws;
    uchar*  Vbp  = (uchar*)(ws + OFF_VB);
    float*  RSI  = ws + OFF_RSI;

    k_proj<<<BB * 32, 256, 0, stream>>>(x, wq, wv, bv, Qt, Vbp);
    k_rowstats<<<BB * 32, 512, 0, stream>>>(Qt, RSI);
    k_attn_pv<<<BB * 16, 1024, 0, stream>>>(Qt, Vbp, RSI, x, wt, bt, gamma, beta,
                                            bn_mean, bn_var, out);
}